// Round 7
// baseline (68.799 us; speedup 1.0000x reference)
//
#include <hip/hip_runtime.h>

// Gram matrix lower-tri extraction: out[b, i*(i-1)/2 + j] = sum_d X[b,i,d]*X[b,j,d], i>j
// B=8192, N=64, D=128, fp32 in/out. bf16 MFMA (16x16x32), one wave per sample.
//
// R6: single-variable experiment vs R5 — nontemporal LOADS only (read stream
// has zero reuse; keep it out of L1/L2 so the cache serves write-line
// assembly). Stores remain normal (R3 showed NT stores regress; R5's aligned
// LDS-staged store path is kept).

typedef __attribute__((ext_vector_type(8))) short bf16x8;
typedef __attribute__((ext_vector_type(4))) float f32x4;

__device__ inline short f2bf(float f) {
    // round-to-nearest-even fp32 -> bf16 (inputs are finite normals)
    unsigned int u = __float_as_uint(f);
    u += 0x7fffu + ((u >> 16) & 1u);
    return (short)(u >> 16);
}

__global__ __launch_bounds__(256) void gram_tril_kernel(const float* __restrict__ X,
                                                        float* __restrict__ out) {
    __shared__ float obuf[4][2016];  // 8064 B per wave, 32 KB per block

    const int wave = threadIdx.x >> 6;
    const int lane = threadIdx.x & 63;
    const int b = blockIdx.x * 4 + wave;

    const float* __restrict__ Xb = X + (size_t)b * (64 * 128);
    const int lr = lane & 15;   // row within 16-row block (fixed by MFMA layout)
    const int lg = lane >> 4;   // quarter-selector within each 64-B chunk

    bf16x8 frag[4][4];
#pragma unroll
    for (int ti = 0; ti < 4; ++ti) {
        const float* rowp = Xb + (size_t)(ti * 16 + lr) * 128 + lg * 4;
#pragma unroll
        for (int q = 0; q < 8; ++q) {
            // wave footprint of this load: rows 0..15, bytes [q*64, q*64+64) each
            const f32x4 a = __builtin_nontemporal_load((const f32x4*)(rowp + q * 16));
            const int ks = q >> 1;
            const int h = (q & 1) * 4;
            frag[ti][ks][h + 0] = f2bf(a.x);
            frag[ti][ks][h + 1] = f2bf(a.y);
            frag[ti][ks][h + 2] = f2bf(a.z);
            frag[ti][ks][h + 3] = f2bf(a.w);
        }
    }

    float* wbuf = obuf[wave];

    // 10 lower-tri tiles (ti >= tj); diagonal tiles masked to strict-lower.
    // Scatter results into the per-wave LDS buffer (cheap there).
#pragma unroll
    for (int ti = 0; ti < 4; ++ti) {
#pragma unroll
        for (int tj = 0; tj <= ti; ++tj) {
            f32x4 acc = {0.f, 0.f, 0.f, 0.f};
#pragma unroll
            for (int ks = 0; ks < 4; ++ks) {
                acc = __builtin_amdgcn_mfma_f32_16x16x32_bf16(frag[ti][ks], frag[tj][ks],
                                                              acc, 0, 0, 0);
            }
            const int j = tj * 16 + lr;  // C/D: col = lane&15
#pragma unroll
            for (int r = 0; r < 4; ++r) {
                const int i = ti * 16 + lg * 4 + r;  // C/D: row = (lane>>4)*4 + reg
                if (ti > tj || i > j) {
                    wbuf[(i * (i - 1)) / 2 + j] = acc[r];
                }
            }
        }
    }

    // Same-wave LDS write->read ordering (no cross-wave sharing, no barrier).
    asm volatile("s_waitcnt lgkmcnt(0)" ::: "memory");

    // Stream out: 7 full chunks of 256 floats (1 KB per instruction, aligned)
    // + tail of 224 floats (lanes 0..55). 2016 = 7*256 + 224.
    float* __restrict__ ob = out + (size_t)b * 2016;
#pragma unroll
    for (int c = 0; c < 7; ++c) {
        const f32x4 v = *(const f32x4*)(wbuf + c * 256 + lane * 4);
        *(f32x4*)(ob + c * 256 + lane * 4) = v;
    }
    if (lane < 56) {
        const f32x4 v = *(const f32x4*)(wbuf + 1792 + lane * 4);
        *(f32x4*)(ob + 1792 + lane * 4) = v;
    }
}

extern "C" void kernel_launch(void* const* d_in, const int* in_sizes, int n_in,
                              void* d_out, int out_size, void* d_ws, size_t ws_size,
                              hipStream_t stream) {
    const float* X = (const float*)d_in[0];
    float* out = (float*)d_out;
    const int B = in_sizes[0] / (64 * 128);  // 8192
    const int blocks = B / 4;                // 4 waves/block, 1 sample/wave
    gram_tril_kernel<<<blocks, 256, 0, stream>>>(X, out);
}

// Round 8
// 65.433 us; speedup vs baseline: 1.0514x; 1.0514x over previous
//
#include <hip/hip_runtime.h>

// Gram matrix lower-tri extraction: out[b, i*(i-1)/2 + j] = sum_d X[b,i,d]*X[b,j,d], i>j
// B=8192, N=64, D=128, fp32 in/out. bf16 MFMA (16x16x32), one wave per sample.
//
// FINAL (= R5, best measured config, 64.75 us):
//  - one wave per sample; fragments loaded straight to registers (no input LDS);
//    k-permutation freedom of the Gram form used to keep loads 64-B contiguous
//    per row (load pattern changes were neutral, but this one costs nothing).
//  - 10 lower-tri MFMA tiles (16x16x32 bf16), diagonal tiles masked to strict-lower.
//  - output staged in per-wave LDS, streamed out as aligned dwordx4 (1 KB/instr):
//    +3% vs exec-masked scalar stores (R5 vs R4).
//  - NO nontemporal ops: NT stores -25% (R3), NT loads -6% (R6) on this pattern.
//  - __launch_bounds__ cap and load-segment reshaping: tested, neutral (R4, R1).
// Effective BW 5.17 TB/s vs 53-us compulsory floor at 6.3 TB/s copy ceiling
// => ~85-90% of achievable incl. fixed launch overhead. Memory-bound roofline.

typedef __attribute__((ext_vector_type(8))) short bf16x8;
typedef __attribute__((ext_vector_type(4))) float f32x4;

__device__ inline short f2bf(float f) {
    // round-to-nearest-even fp32 -> bf16 (inputs are finite normals)
    unsigned int u = __float_as_uint(f);
    u += 0x7fffu + ((u >> 16) & 1u);
    return (short)(u >> 16);
}

__global__ __launch_bounds__(256) void gram_tril_kernel(const float* __restrict__ X,
                                                        float* __restrict__ out) {
    __shared__ float obuf[4][2016];  // 8064 B per wave, 32 KB per block

    const int wave = threadIdx.x >> 6;
    const int lane = threadIdx.x & 63;
    const int b = blockIdx.x * 4 + wave;

    const float* __restrict__ Xb = X + (size_t)b * (64 * 128);
    const int lr = lane & 15;   // row within 16-row block (fixed by MFMA layout)
    const int lg = lane >> 4;   // quarter-selector within each 64-B chunk

    bf16x8 frag[4][4];
#pragma unroll
    for (int ti = 0; ti < 4; ++ti) {
        const float* rowp = Xb + (size_t)(ti * 16 + lr) * 128 + lg * 4;
#pragma unroll
        for (int q = 0; q < 8; ++q) {
            // wave footprint of this load: rows 0..15, bytes [q*64, q*64+64) each
            const float4 a = *(const float4*)(rowp + q * 16);
            const int ks = q >> 1;
            const int h = (q & 1) * 4;
            frag[ti][ks][h + 0] = f2bf(a.x);
            frag[ti][ks][h + 1] = f2bf(a.y);
            frag[ti][ks][h + 2] = f2bf(a.z);
            frag[ti][ks][h + 3] = f2bf(a.w);
        }
    }

    float* wbuf = obuf[wave];

    // 10 lower-tri tiles (ti >= tj); diagonal tiles masked to strict-lower.
    // Scatter results into the per-wave LDS buffer (cheap there).
#pragma unroll
    for (int ti = 0; ti < 4; ++ti) {
#pragma unroll
        for (int tj = 0; tj <= ti; ++tj) {
            f32x4 acc = {0.f, 0.f, 0.f, 0.f};
#pragma unroll
            for (int ks = 0; ks < 4; ++ks) {
                acc = __builtin_amdgcn_mfma_f32_16x16x32_bf16(frag[ti][ks], frag[tj][ks],
                                                              acc, 0, 0, 0);
            }
            const int j = tj * 16 + lr;  // C/D: col = lane&15
#pragma unroll
            for (int r = 0; r < 4; ++r) {
                const int i = ti * 16 + lg * 4 + r;  // C/D: row = (lane>>4)*4 + reg
                if (ti > tj || i > j) {
                    wbuf[(i * (i - 1)) / 2 + j] = acc[r];
                }
            }
        }
    }

    // Same-wave LDS write->read ordering (no cross-wave sharing, no barrier).
    asm volatile("s_waitcnt lgkmcnt(0)" ::: "memory");

    // Stream out: 7 full chunks of 256 floats (1 KB per instruction, aligned)
    // + tail of 224 floats (lanes 0..55). 2016 = 7*256 + 224.
    float* __restrict__ ob = out + (size_t)b * 2016;
#pragma unroll
    for (int c = 0; c < 7; ++c) {
        const f32x4 v = *(const f32x4*)(wbuf + c * 256 + lane * 4);
        *(f32x4*)(ob + c * 256 + lane * 4) = v;
    }
    if (lane < 56) {
        const f32x4 v = *(const f32x4*)(wbuf + 1792 + lane * 4);
        *(f32x4*)(ob + 1792 + lane * 4) = v;
    }
}

extern "C" void kernel_launch(void* const* d_in, const int* in_sizes, int n_in,
                              void* d_out, int out_size, void* d_ws, size_t ws_size,
                              hipStream_t stream) {
    const float* X = (const float*)d_in[0];
    float* out = (float*)d_out;
    const int B = in_sizes[0] / (64 * 128);  // 8192
    const int blocks = B / 4;                // 4 waves/block, 1 sample/wave
    gram_tril_kernel<<<blocks, 256, 0, stream>>>(X, out);
}